// Round 1
// baseline (713.455 us; speedup 1.0000x reference)
//
#include <hip/hip_runtime.h>

#define FDIM 80
#define RDIM 20
#define TPB  320   // 5 waves; thread -> column j = t%80, row-group rg = t/80
#define PPB  64    // pairs per block (pair kernel)
#define UPB  128   // (pair,side) units per block = 2*PPB
#define ROWS 64    // atom rows per block (atom kernel)

__device__ __forceinline__ float sp_f(float x){
  // softplus, numerically stable: max(x,0) + log(1+exp(-|x|))
  float e = __expf(-fabsf(x));
  return fmaxf(x, 0.f) + __logf(1.f + e);
}

// ---------------------------------------------------------------------------
// Pair kernel: for each pair p and side s:
//   fmsg = sp( sp(features[idx]) @ WJ + bJ )
//   aevt = radial_aev[p] @ Wg + bg
//   atomicAdd(proto[idx], aevt * fmsg)
// ---------------------------------------------------------------------------
__global__ __launch_bounds__(TPB) void pair_kernel(
    const float* __restrict__ features,
    const float* __restrict__ aev,
    const int*   __restrict__ idx12,
    const float* __restrict__ Wg, const float* __restrict__ bg,
    const float* __restrict__ WJ, const float* __restrict__ bJ,
    float* __restrict__ proto, int P)
{
  __shared__ __align__(16) float xs[UPB][FDIM + 4];  // sp(features) rows
  __shared__ float al[PPB][RDIM];                    // aev rows
  __shared__ int   idxl[UPB];

  const int t  = threadIdx.x;
  const int p0 = blockIdx.x * PPB;
  const int prem = min(PPB, P - p0);

  if (t < UPB){
    int pp = t >> 1;
    idxl[t] = (pp < prem) ? idx12[(size_t)(t & 1) * P + p0 + pp] : 0;
  }
  for (int i = t; i < PPB * RDIM; i += TPB){
    int pp = i / RDIM, rr = i % RDIM;
    al[pp][rr] = (pp < prem) ? aev[(size_t)(p0 + pp) * RDIM + rr] : 0.f;
  }
  __syncthreads();

  // gather + softplus into LDS
  for (int i = t; i < UPB * FDIM; i += TPB){
    int u = i / FDIM, c = i % FDIM;
    xs[u][c] = sp_f(features[(size_t)idxl[u] * FDIM + c]);
  }

  // W columns into registers (coalesced: lanes have consecutive j)
  const int j  = t % FDIM;
  const int rg = t / FDIM;
  float wcJ[FDIM];
  #pragma unroll
  for (int k = 0; k < FDIM; k++) wcJ[k] = WJ[k * FDIM + j];
  float wcG[RDIM];
  #pragma unroll
  for (int r = 0; r < RDIM; r++) wcG[r] = Wg[r * FDIM + j];
  const float bJj = bJ[j], bgj = bg[j];
  __syncthreads();

  #pragma unroll 1
  for (int ui = 0; ui < UPB / 4; ui++){
    int u  = rg + 4 * ui;
    int pp = u >> 1;
    if (pp >= prem) continue;
    const float4* srow = (const float4*)(&xs[u][0]);
    float acc = bJj;
    #pragma unroll
    for (int kk = 0; kk < FDIM / 4; kk++){
      float4 s = srow[kk];
      acc += s.x * wcJ[4*kk] + s.y * wcJ[4*kk+1] + s.z * wcJ[4*kk+2] + s.w * wcJ[4*kk+3];
    }
    float fm = sp_f(acc);
    float av = bgj;
    #pragma unroll
    for (int r = 0; r < RDIM; r++) av += al[pp][r] * wcG[r];
    atomicAdd(&proto[(size_t)idxl[u] * FDIM + j], av * fm);
  }
}

// ---------------------------------------------------------------------------
// Residual block on a 64x80 LDS tile: xb = sp(xa@W1+b1); xa = sp(xb@W2+b2+xa)
// ---------------------------------------------------------------------------
__device__ __forceinline__ void res_block(
    float (* __restrict__ xa)[FDIM + 4], float (* __restrict__ xb)[FDIM + 4],
    const float* __restrict__ W1, const float* __restrict__ b1,
    const float* __restrict__ W2, const float* __restrict__ b2,
    int j, int rg)
{
  {
    float wc[FDIM];
    #pragma unroll
    for (int k = 0; k < FDIM; k++) wc[k] = W1[k * FDIM + j];
    float bj = b1[j];
    #pragma unroll 1
    for (int ui = 0; ui < ROWS / 4; ui++){
      int u = rg + 4 * ui;
      const float4* srow = (const float4*)(&xa[u][0]);
      float acc = bj;
      #pragma unroll
      for (int kk = 0; kk < FDIM / 4; kk++){
        float4 s = srow[kk];
        acc += s.x * wc[4*kk] + s.y * wc[4*kk+1] + s.z * wc[4*kk+2] + s.w * wc[4*kk+3];
      }
      xb[u][j] = sp_f(acc);
    }
  }
  __syncthreads();
  {
    float wc[FDIM];
    #pragma unroll
    for (int k = 0; k < FDIM; k++) wc[k] = W2[k * FDIM + j];
    float bj = b2[j];
    #pragma unroll 1
    for (int ui = 0; ui < ROWS / 4; ui++){
      int u = rg + 4 * ui;
      const float4* srow = (const float4*)(&xb[u][0]);
      float acc = bj + xa[u][j];
      #pragma unroll
      for (int kk = 0; kk < FDIM / 4; kk++){
        float4 s = srow[kk];
        acc += s.x * wc[4*kk] + s.y * wc[4*kk+1] + s.z * wc[4*kk+2] + s.w * wc[4*kk+3];
      }
      xa[u][j] = sp_f(acc);
    }
  }
  __syncthreads();
}

// ---------------------------------------------------------------------------
// Atom kernel: everything after the scatter, fused. 64 rows per block.
// ---------------------------------------------------------------------------
__global__ __launch_bounds__(TPB) void atom_kernel(
    const int*   __restrict__ species,
    const float* __restrict__ features,
    const float* __restrict__ proto_in,
    const float* __restrict__ WI,  const float* __restrict__ bI,
    const float* __restrict__ iW1, const float* __restrict__ ib1,
    const float* __restrict__ iW2, const float* __restrict__ ib2,
    const float* __restrict__ gate,
    const float* __restrict__ Wint, const float* __restrict__ bint,
    const float* __restrict__ aW1, const float* __restrict__ ab1,
    const float* __restrict__ aW2, const float* __restrict__ ab2,
    const float* __restrict__ oW1, const float* __restrict__ ob1,
    const float* __restrict__ oW2, const float* __restrict__ ob2,
    const float* __restrict__ Wout, const float* __restrict__ bout,
    float* __restrict__ out_e, float* __restrict__ out_f, int N)
{
  __shared__ __align__(16) float xa[ROWS][FDIM + 4];
  __shared__ __align__(16) float xb[ROWS][FDIM + 4];
  __shared__ __align__(16) float xf[ROWS][FDIM + 4];
  __shared__ float mskl[ROWS];

  const int t    = threadIdx.x;
  const int base = blockIdx.x * ROWS;

  for (int i = t; i < ROWS * FDIM; i += TPB){
    int r = i / FDIM, c = i % FDIM;
    size_t g = (size_t)(base + r) * FDIM + c;
    xa[r][c] = proto_in[g];
    xf[r][c] = features[g];
  }
  if (t < ROWS) mskl[t] = (species[base + t] != -1) ? 1.f : 0.f;
  __syncthreads();

  const int j  = t % FDIM;
  const int rg = t / FDIM;

  // proto += (features @ WI + bI) * mask
  {
    float wc[FDIM];
    #pragma unroll
    for (int k = 0; k < FDIM; k++) wc[k] = WI[k * FDIM + j];
    float bj = bI[j];
    #pragma unroll 1
    for (int ui = 0; ui < ROWS / 4; ui++){
      int u = rg + 4 * ui;
      const float4* srow = (const float4*)(&xf[u][0]);
      float acc = bj;
      #pragma unroll
      for (int kk = 0; kk < FDIM / 4; kk++){
        float4 s = srow[kk];
        acc += s.x * wc[4*kk] + s.y * wc[4*kk+1] + s.z * wc[4*kk+2] + s.w * wc[4*kk+3];
      }
      xa[u][j] += acc * mskl[u];
    }
  }
  __syncthreads();

  // message = res_stack(proto, iW*)
  #pragma unroll 1
  for (int ir = 0; ir < 3; ir++)
    res_block(xa, xb, iW1 + ir * FDIM * FDIM, ib1 + ir * FDIM,
                      iW2 + ir * FDIM * FDIM, ib2 + ir * FDIM, j, rg);

  // nd = features*gate + sp(message) @ Wint + bint
  for (int i = t; i < ROWS * FDIM; i += TPB){
    int r = i / FDIM, c = i % FDIM;
    xb[r][c] = sp_f(xa[r][c]);
  }
  __syncthreads();
  {
    float wc[FDIM];
    #pragma unroll
    for (int k = 0; k < FDIM; k++) wc[k] = Wint[k * FDIM + j];
    float bj = bint[j];
    float gj = gate[j];
    #pragma unroll 1
    for (int ui = 0; ui < ROWS / 4; ui++){
      int u = rg + 4 * ui;
      const float4* srow = (const float4*)(&xb[u][0]);
      float acc = bj;
      #pragma unroll
      for (int kk = 0; kk < FDIM / 4; kk++){
        float4 s = srow[kk];
        acc += s.x * wc[4*kk] + s.y * wc[4*kk+1] + s.z * wc[4*kk+2] + s.w * wc[4*kk+3];
      }
      xa[u][j] = xf[u][j] * gj + acc;
    }
  }
  __syncthreads();

  // nd = res_stack(nd, aW*)
  #pragma unroll 1
  for (int ir = 0; ir < 3; ir++)
    res_block(xa, xb, aW1 + ir * FDIM * FDIM, ab1 + ir * FDIM,
                      aW2 + ir * FDIM * FDIM, ab2 + ir * FDIM, j, rg);

  // out_features = nd * mask
  for (int i = t; i < ROWS * FDIM; i += TPB){
    int r = i / FDIM, c = i % FDIM;
    out_f[(size_t)(base + r) * FDIM + c] = xa[r][c] * mskl[r];
  }
  // (no barrier needed: o-stack writes xa only after its internal barrier)

  // t3 = res_stack(nd, oW*)
  #pragma unroll 1
  for (int ir = 0; ir < 3; ir++)
    res_block(xa, xb, oW1 + ir * FDIM * FDIM, ob1 + ir * FDIM,
                      oW2 + ir * FDIM * FDIM, ob2 + ir * FDIM, j, rg);

  // energies = (sp(t3) @ Wout + bout) * mask
  for (int i = t; i < ROWS * FDIM; i += TPB){
    int r = i / FDIM, c = i % FDIM;
    xb[r][c] = sp_f(xa[r][c]);
  }
  __syncthreads();
  if (t < ROWS){
    float acc = bout[0];
    #pragma unroll
    for (int k = 0; k < FDIM; k++) acc += xb[t][k] * Wout[k];
    out_e[base + t] = acc * mskl[t];
  }
}

// ---------------------------------------------------------------------------
extern "C" void kernel_launch(void* const* d_in, const int* in_sizes, int n_in,
                              void* d_out, int out_size, void* d_ws, size_t ws_size,
                              hipStream_t stream) {
  const int*   species  = (const int*)  d_in[0];
  const float* features = (const float*)d_in[1];
  const float* aev      = (const float*)d_in[2];
  const int*   idx12    = (const int*)  d_in[3];
  const float* WI   = (const float*)d_in[4];  const float* bI   = (const float*)d_in[5];
  const float* Wg   = (const float*)d_in[6];  const float* bg   = (const float*)d_in[7];
  const float* WJ   = (const float*)d_in[8];  const float* bJ   = (const float*)d_in[9];
  const float* iW1  = (const float*)d_in[10]; const float* ib1  = (const float*)d_in[11];
  const float* iW2  = (const float*)d_in[12]; const float* ib2  = (const float*)d_in[13];
  const float* gate = (const float*)d_in[14];
  const float* Wint = (const float*)d_in[15]; const float* bint = (const float*)d_in[16];
  const float* aW1  = (const float*)d_in[17]; const float* ab1  = (const float*)d_in[18];
  const float* aW2  = (const float*)d_in[19]; const float* ab2  = (const float*)d_in[20];
  const float* oW1  = (const float*)d_in[21]; const float* ob1  = (const float*)d_in[22];
  const float* oW2  = (const float*)d_in[23]; const float* ob2  = (const float*)d_in[24];
  const float* Wout = (const float*)d_in[25]; const float* bout = (const float*)d_in[26];

  const int N = in_sizes[1] / FDIM;   // 16384
  const int P = in_sizes[2] / RDIM;   // 393216

  float* proto = (float*)d_ws;
  float* out_e = (float*)d_out;
  float* out_f = out_e + N;

  hipMemsetAsync(proto, 0, (size_t)N * FDIM * sizeof(float), stream);

  dim3 pgrid((P + PPB - 1) / PPB);
  pair_kernel<<<pgrid, TPB, 0, stream>>>(features, aev, idx12, Wg, bg, WJ, bJ, proto, P);

  dim3 agrid((N + ROWS - 1) / ROWS);
  atom_kernel<<<agrid, TPB, 0, stream>>>(species, features, proto,
      WI, bI, iW1, ib1, iW2, ib2, gate, Wint, bint,
      aW1, ab1, aW2, ab2, oW1, ob1, oW2, ob2, Wout, bout,
      out_e, out_f, N);
}

// Round 2
// 416.355 us; speedup vs baseline: 1.7136x; 1.7136x over previous
//
#include <hip/hip_runtime.h>

#define FDIM 80
#define RDIM 20
#define TPB  320   // 5 waves; thread -> column j = t%80, row-group rg = t/80
#define PPB  64    // pairs per block (pair kernel)
#define UPB  128   // (pair,side) units per block = 2*PPB
#define ROWS 64    // atom rows per block (atom/msg kernels)

__device__ __forceinline__ float sp_f(float x){
  // softplus, numerically stable: max(x,0) + log(1+exp(-|x|))
  float e = __expf(-fabsf(x));
  return fmaxf(x, 0.f) + __logf(1.f + e);
}

// ---------------------------------------------------------------------------
// msg kernel: msg_table[n] = sp( sp(features[n]) @ WJ + bJ )   for n in [0,N)
// One 64-row tile per block. 256 blocks.
// ---------------------------------------------------------------------------
__global__ __launch_bounds__(TPB) void msg_kernel(
    const float* __restrict__ features,
    const float* __restrict__ WJ, const float* __restrict__ bJ,
    float* __restrict__ msg_table, int N)
{
  __shared__ __align__(16) float xs[ROWS][FDIM + 4];
  const int t    = threadIdx.x;
  const int base = blockIdx.x * ROWS;

  for (int i = t; i < ROWS * FDIM; i += TPB){
    int r = i / FDIM, c = i % FDIM;
    xs[r][c] = sp_f(features[(size_t)(base + r) * FDIM + c]);
  }
  const int j  = t % FDIM;
  const int rg = t / FDIM;
  float wc[FDIM];
  #pragma unroll
  for (int k = 0; k < FDIM; k++) wc[k] = WJ[k * FDIM + j];
  const float bj = bJ[j];
  __syncthreads();

  #pragma unroll 1
  for (int ui = 0; ui < ROWS / 4; ui++){
    int u = rg + 4 * ui;
    const float4* srow = (const float4*)(&xs[u][0]);
    float acc = bj;
    #pragma unroll
    for (int kk = 0; kk < FDIM / 4; kk++){
      float4 s = srow[kk];
      acc += s.x * wc[4*kk] + s.y * wc[4*kk+1] + s.z * wc[4*kk+2] + s.w * wc[4*kk+3];
    }
    msg_table[(size_t)(base + u) * FDIM + j] = sp_f(acc);
  }
}

// ---------------------------------------------------------------------------
// Pair kernel v2: per pair p:
//   aevt = radial_aev[p] @ Wg + bg          (shared across both sides)
//   for side s: atomicAdd(proto[idx[s][p]], aevt * msg_table[idx[s][p]])
// ---------------------------------------------------------------------------
__global__ __launch_bounds__(TPB) void pair_kernel2(
    const float* __restrict__ msg_table,
    const float* __restrict__ aev,
    const int*   __restrict__ idx12,
    const float* __restrict__ Wg, const float* __restrict__ bg,
    float* __restrict__ proto, int P)
{
  __shared__ float al[PPB][RDIM];   // aev rows
  __shared__ int   idxl[UPB];

  const int t  = threadIdx.x;
  const int p0 = blockIdx.x * PPB;
  const int prem = min(PPB, P - p0);

  if (t < UPB){
    int pp = t >> 1;
    idxl[t] = (pp < prem) ? idx12[(size_t)(t & 1) * P + p0 + pp] : 0;
  }
  for (int i = t; i < PPB * RDIM; i += TPB){
    int pp = i / RDIM, rr = i % RDIM;
    al[pp][rr] = (pp < prem) ? aev[(size_t)(p0 + pp) * RDIM + rr] : 0.f;
  }

  const int j  = t % FDIM;
  const int rg = t / FDIM;
  float wcG[RDIM];
  #pragma unroll
  for (int r = 0; r < RDIM; r++) wcG[r] = Wg[r * FDIM + j];
  const float bgj = bg[j];
  __syncthreads();

  #pragma unroll 1
  for (int pi = 0; pi < PPB / 4; pi++){
    int pp = rg + 4 * pi;
    if (pp >= prem) continue;
    float av = bgj;
    #pragma unroll
    for (int r = 0; r < RDIM; r++) av += al[pp][r] * wcG[r];
    #pragma unroll
    for (int s = 0; s < 2; s++){
      int ia = idxl[2 * pp + s];
      float m = msg_table[(size_t)ia * FDIM + j];
      atomicAdd(&proto[(size_t)ia * FDIM + j], av * m);
    }
  }
}

// ---------------------------------------------------------------------------
// Residual block on a 64x80 LDS tile: xb = sp(xa@W1+b1); xa = sp(xb@W2+b2+xa)
// ---------------------------------------------------------------------------
__device__ __forceinline__ void res_block(
    float (* __restrict__ xa)[FDIM + 4], float (* __restrict__ xb)[FDIM + 4],
    const float* __restrict__ W1, const float* __restrict__ b1,
    const float* __restrict__ W2, const float* __restrict__ b2,
    int j, int rg)
{
  {
    float wc[FDIM];
    #pragma unroll
    for (int k = 0; k < FDIM; k++) wc[k] = W1[k * FDIM + j];
    float bj = b1[j];
    #pragma unroll 1
    for (int ui = 0; ui < ROWS / 4; ui++){
      int u = rg + 4 * ui;
      const float4* srow = (const float4*)(&xa[u][0]);
      float acc = bj;
      #pragma unroll
      for (int kk = 0; kk < FDIM / 4; kk++){
        float4 s = srow[kk];
        acc += s.x * wc[4*kk] + s.y * wc[4*kk+1] + s.z * wc[4*kk+2] + s.w * wc[4*kk+3];
      }
      xb[u][j] = sp_f(acc);
    }
  }
  __syncthreads();
  {
    float wc[FDIM];
    #pragma unroll
    for (int k = 0; k < FDIM; k++) wc[k] = W2[k * FDIM + j];
    float bj = b2[j];
    #pragma unroll 1
    for (int ui = 0; ui < ROWS / 4; ui++){
      int u = rg + 4 * ui;
      const float4* srow = (const float4*)(&xb[u][0]);
      float acc = bj + xa[u][j];
      #pragma unroll
      for (int kk = 0; kk < FDIM / 4; kk++){
        float4 s = srow[kk];
        acc += s.x * wc[4*kk] + s.y * wc[4*kk+1] + s.z * wc[4*kk+2] + s.w * wc[4*kk+3];
      }
      xa[u][j] = sp_f(acc);
    }
  }
  __syncthreads();
}

// ---------------------------------------------------------------------------
// Atom kernel: everything after the scatter, fused. 64 rows per block.
// ---------------------------------------------------------------------------
__global__ __launch_bounds__(TPB) void atom_kernel(
    const int*   __restrict__ species,
    const float* __restrict__ features,
    const float* __restrict__ proto_in,
    const float* __restrict__ WI,  const float* __restrict__ bI,
    const float* __restrict__ iW1, const float* __restrict__ ib1,
    const float* __restrict__ iW2, const float* __restrict__ ib2,
    const float* __restrict__ gate,
    const float* __restrict__ Wint, const float* __restrict__ bint,
    const float* __restrict__ aW1, const float* __restrict__ ab1,
    const float* __restrict__ aW2, const float* __restrict__ ab2,
    const float* __restrict__ oW1, const float* __restrict__ ob1,
    const float* __restrict__ oW2, const float* __restrict__ ob2,
    const float* __restrict__ Wout, const float* __restrict__ bout,
    float* __restrict__ out_e, float* __restrict__ out_f, int N)
{
  __shared__ __align__(16) float xa[ROWS][FDIM + 4];
  __shared__ __align__(16) float xb[ROWS][FDIM + 4];
  __shared__ __align__(16) float xf[ROWS][FDIM + 4];
  __shared__ float mskl[ROWS];

  const int t    = threadIdx.x;
  const int base = blockIdx.x * ROWS;

  for (int i = t; i < ROWS * FDIM; i += TPB){
    int r = i / FDIM, c = i % FDIM;
    size_t g = (size_t)(base + r) * FDIM + c;
    xa[r][c] = proto_in[g];
    xf[r][c] = features[g];
  }
  if (t < ROWS) mskl[t] = (species[base + t] != -1) ? 1.f : 0.f;
  __syncthreads();

  const int j  = t % FDIM;
  const int rg = t / FDIM;

  // proto += (features @ WI + bI) * mask
  {
    float wc[FDIM];
    #pragma unroll
    for (int k = 0; k < FDIM; k++) wc[k] = WI[k * FDIM + j];
    float bj = bI[j];
    #pragma unroll 1
    for (int ui = 0; ui < ROWS / 4; ui++){
      int u = rg + 4 * ui;
      const float4* srow = (const float4*)(&xf[u][0]);
      float acc = bj;
      #pragma unroll
      for (int kk = 0; kk < FDIM / 4; kk++){
        float4 s = srow[kk];
        acc += s.x * wc[4*kk] + s.y * wc[4*kk+1] + s.z * wc[4*kk+2] + s.w * wc[4*kk+3];
      }
      xa[u][j] += acc * mskl[u];
    }
  }
  __syncthreads();

  // message = res_stack(proto, iW*)
  #pragma unroll 1
  for (int ir = 0; ir < 3; ir++)
    res_block(xa, xb, iW1 + ir * FDIM * FDIM, ib1 + ir * FDIM,
                      iW2 + ir * FDIM * FDIM, ib2 + ir * FDIM, j, rg);

  // nd = features*gate + sp(message) @ Wint + bint
  for (int i = t; i < ROWS * FDIM; i += TPB){
    int r = i / FDIM, c = i % FDIM;
    xb[r][c] = sp_f(xa[r][c]);
  }
  __syncthreads();
  {
    float wc[FDIM];
    #pragma unroll
    for (int k = 0; k < FDIM; k++) wc[k] = Wint[k * FDIM + j];
    float bj = bint[j];
    float gj = gate[j];
    #pragma unroll 1
    for (int ui = 0; ui < ROWS / 4; ui++){
      int u = rg + 4 * ui;
      const float4* srow = (const float4*)(&xb[u][0]);
      float acc = bj;
      #pragma unroll
      for (int kk = 0; kk < FDIM / 4; kk++){
        float4 s = srow[kk];
        acc += s.x * wc[4*kk] + s.y * wc[4*kk+1] + s.z * wc[4*kk+2] + s.w * wc[4*kk+3];
      }
      xa[u][j] = xf[u][j] * gj + acc;
    }
  }
  __syncthreads();

  // nd = res_stack(nd, aW*)
  #pragma unroll 1
  for (int ir = 0; ir < 3; ir++)
    res_block(xa, xb, aW1 + ir * FDIM * FDIM, ab1 + ir * FDIM,
                      aW2 + ir * FDIM * FDIM, ab2 + ir * FDIM, j, rg);

  // out_features = nd * mask
  for (int i = t; i < ROWS * FDIM; i += TPB){
    int r = i / FDIM, c = i % FDIM;
    out_f[(size_t)(base + r) * FDIM + c] = xa[r][c] * mskl[r];
  }
  // (no barrier needed: o-stack writes xa only after its internal barrier)

  // t3 = res_stack(nd, oW*)
  #pragma unroll 1
  for (int ir = 0; ir < 3; ir++)
    res_block(xa, xb, oW1 + ir * FDIM * FDIM, ob1 + ir * FDIM,
                      oW2 + ir * FDIM * FDIM, ob2 + ir * FDIM, j, rg);

  // energies = (sp(t3) @ Wout + bout) * mask
  for (int i = t; i < ROWS * FDIM; i += TPB){
    int r = i / FDIM, c = i % FDIM;
    xb[r][c] = sp_f(xa[r][c]);
  }
  __syncthreads();
  if (t < ROWS){
    float acc = bout[0];
    #pragma unroll
    for (int k = 0; k < FDIM; k++) acc += xb[t][k] * Wout[k];
    out_e[base + t] = acc * mskl[t];
  }
}

// ---------------------------------------------------------------------------
extern "C" void kernel_launch(void* const* d_in, const int* in_sizes, int n_in,
                              void* d_out, int out_size, void* d_ws, size_t ws_size,
                              hipStream_t stream) {
  const int*   species  = (const int*)  d_in[0];
  const float* features = (const float*)d_in[1];
  const float* aev      = (const float*)d_in[2];
  const int*   idx12    = (const int*)  d_in[3];
  const float* WI   = (const float*)d_in[4];  const float* bI   = (const float*)d_in[5];
  const float* Wg   = (const float*)d_in[6];  const float* bg   = (const float*)d_in[7];
  const float* WJ   = (const float*)d_in[8];  const float* bJ   = (const float*)d_in[9];
  const float* iW1  = (const float*)d_in[10]; const float* ib1  = (const float*)d_in[11];
  const float* iW2  = (const float*)d_in[12]; const float* ib2  = (const float*)d_in[13];
  const float* gate = (const float*)d_in[14];
  const float* Wint = (const float*)d_in[15]; const float* bint = (const float*)d_in[16];
  const float* aW1  = (const float*)d_in[17]; const float* ab1  = (const float*)d_in[18];
  const float* aW2  = (const float*)d_in[19]; const float* ab2  = (const float*)d_in[20];
  const float* oW1  = (const float*)d_in[21]; const float* ob1  = (const float*)d_in[22];
  const float* oW2  = (const float*)d_in[23]; const float* ob2  = (const float*)d_in[24];
  const float* Wout = (const float*)d_in[25]; const float* bout = (const float*)d_in[26];

  const int N = in_sizes[1] / FDIM;   // 16384
  const int P = in_sizes[2] / RDIM;   // 393216

  float* proto = (float*)d_ws;                       // N*FDIM floats
  float* msgt  = proto + (size_t)N * FDIM;           // N*FDIM floats
  float* out_e = (float*)d_out;
  float* out_f = out_e + N;

  hipMemsetAsync(proto, 0, (size_t)N * FDIM * sizeof(float), stream);

  msg_kernel<<<(N + ROWS - 1) / ROWS, TPB, 0, stream>>>(features, WJ, bJ, msgt, N);

  pair_kernel2<<<(P + PPB - 1) / PPB, TPB, 0, stream>>>(msgt, aev, idx12, Wg, bg, proto, P);

  atom_kernel<<<(N + ROWS - 1) / ROWS, TPB, 0, stream>>>(species, features, proto,
      WI, bI, iW1, ib1, iW2, ib2, gate, Wint, bint,
      aW1, ab1, aW2, ab2, oW1, ob1, oW2, ob2, Wout, bout,
      out_e, out_f, N);
}

// Round 3
// 231.548 us; speedup vs baseline: 3.0812x; 1.7981x over previous
//
#include <hip/hip_runtime.h>
#include <hip/hip_bf16.h>

#define FDIM 80
#define RDIM 20
#define KP   96      // padded K for MFMA (3 x 32)
#define LDP  104     // LDS row stride (bf16): 208B, 16B-aligned, 2-way-max banks
#define WROW 96      // Wt row stride (bf16)

typedef float  f32x4  __attribute__((ext_vector_type(4)));
typedef short  bf16x8 __attribute__((ext_vector_type(8)));

__device__ __forceinline__ float sp_f(float x){
  float e = __expf(-fabsf(x));
  return fmaxf(x, 0.f) + __logf(1.f + e);
}
__device__ __forceinline__ __hip_bfloat16 tob(float x){ return __float2bfloat16(x); }

// ---------------------------------------------------------------------------
// Weight prep: Wt[slot][j][k] = bf16(W[k][j]), zero-padded k in [80,96)
// ---------------------------------------------------------------------------
struct WPtrs { const float* p[21]; };

__global__ __launch_bounds__(256) void prep_weights(WPtrs wp, __hip_bfloat16* __restrict__ wt){
  const float* W = wp.p[blockIdx.x];
  __hip_bfloat16* dst = wt + (size_t)blockIdx.x * FDIM * WROW;
  for (int i = threadIdx.x; i < FDIM * WROW; i += 256){
    int j = i / WROW, k = i - j * WROW;
    dst[i] = __float2bfloat16(k < FDIM ? W[k * FDIM + j] : 0.f);
  }
}

// ---------------------------------------------------------------------------
// Scatter: R[n][r] += aev[p][r] for each incident (pair,side); deg[n] += 1
// ---------------------------------------------------------------------------
__global__ __launch_bounds__(256) void scatter_R(const float* __restrict__ aev,
    const int* __restrict__ idx12, float* __restrict__ R, int P){
  int g = blockIdx.x * 256 + threadIdx.x;
  if (g >= P * RDIM) return;
  float v = aev[g];
  int p = g / RDIM, r = g - p * RDIM;
  int i1 = idx12[p], i2 = idx12[P + p];
  atomicAdd(&R[(size_t)i1 * RDIM + r], v);
  atomicAdd(&R[(size_t)i2 * RDIM + r], v);
}

__global__ __launch_bounds__(256) void deg_kernel(const int* __restrict__ idx12,
    float* __restrict__ deg, int P){
  int p = blockIdx.x * 256 + threadIdx.x;
  if (p >= P) return;
  atomicAdd(&deg[idx12[p]], 1.f);
  atomicAdd(&deg[idx12[P + p]], 1.f);
}

// ---------------------------------------------------------------------------
// S[n] = R[n] @ Wg + deg[n]*bg
// ---------------------------------------------------------------------------
#define TPB2 320
__global__ __launch_bounds__(TPB2) void aevt_kernel(const float* __restrict__ R,
    const float* __restrict__ deg, const float* __restrict__ Wg,
    const float* __restrict__ bg, float* __restrict__ S, int N)
{
  __shared__ float Rl[64][RDIM];
  __shared__ float dl[64];
  const int t = threadIdx.x;
  const int base = blockIdx.x * 64;
  for (int i = t; i < 64 * RDIM; i += TPB2){
    int u = i / RDIM, r = i - u * RDIM;
    Rl[u][r] = R[(size_t)(base + u) * RDIM + r];
  }
  if (t < 64) dl[t] = deg[base + t];
  const int j = t % FDIM, rg = t / FDIM;
  float wc[RDIM];
  #pragma unroll
  for (int r = 0; r < RDIM; r++) wc[r] = Wg[r * FDIM + j];
  float bgj = bg[j];
  __syncthreads();
  #pragma unroll 1
  for (int ui = 0; ui < 16; ui++){
    int u = rg + 4 * ui;
    float acc = dl[u] * bgj;
    #pragma unroll
    for (int r = 0; r < RDIM; r++) acc += Rl[u][r] * wc[r];
    S[(size_t)(base + u) * FDIM + j] = acc;
  }
}

// ---------------------------------------------------------------------------
// MFMA helpers. Wave owns 16 rows. A-frag: m=lane&15, k=(lane>>4)*8+e.
// C/D: col=lane&15 (+16*nt), row=(lane>>4)*4+reg  [m89-verified]
// ---------------------------------------------------------------------------
__device__ __forceinline__ void mfma_layer(f32x4 acc[5],
    const __hip_bfloat16 (*in)[LDP], int arow, int kb, int j0,
    const __hip_bfloat16* __restrict__ wtm, const float* __restrict__ bias)
{
  #pragma unroll
  for (int nt = 0; nt < 5; nt++){
    float b = bias[16*nt + j0];
    acc[nt] = (f32x4){b, b, b, b};
  }
  #pragma unroll
  for (int ks = 0; ks < 3; ks++){
    bf16x8 a = *(const bf16x8*)(const void*)&in[arow][kb + ks*32];
    #pragma unroll
    for (int nt = 0; nt < 5; nt++){
      bf16x8 bf = *(const bf16x8*)(const void*)&wtm[(size_t)(16*nt + j0) * WROW + kb + ks*32];
      acc[nt] = __builtin_amdgcn_mfma_f32_16x16x32_bf16(a, bf, acc[nt], 0, 0, 0);
    }
  }
}

__device__ __forceinline__ void res_mfma(f32x4 cur[5],
    __hip_bfloat16 (*bA)[LDP], __hip_bfloat16 (*bB)[LDP],
    int arow, int kb, int j0, int r0,
    const __hip_bfloat16* __restrict__ w1, const float* __restrict__ b1,
    const __hip_bfloat16* __restrict__ w2, const float* __restrict__ b2)
{
  f32x4 acc[5];
  mfma_layer(acc, bA, arow, kb, j0, w1, b1);
  #pragma unroll
  for (int nt = 0; nt < 5; nt++){
    int col = 16*nt + j0;
    #pragma unroll
    for (int i = 0; i < 4; i++) bB[r0 + i][col] = tob(sp_f(acc[nt][i]));
  }
  __syncthreads();
  mfma_layer(acc, bB, arow, kb, j0, w2, b2);
  #pragma unroll
  for (int nt = 0; nt < 5; nt++){
    int col = 16*nt + j0;
    #pragma unroll
    for (int i = 0; i < 4; i++){
      cur[nt][i] = sp_f(acc[nt][i] + cur[nt][i]);
      bA[r0 + i][col] = tob(cur[nt][i]);
    }
  }
  __syncthreads();
}

// ---------------------------------------------------------------------------
// Atom kernel: 64 atoms/block, 4 waves x 16-row strips, 21 bf16 MFMA matmuls
// ---------------------------------------------------------------------------
__global__ __launch_bounds__(256) void atom_mfma(
    const int*   __restrict__ species,
    const float* __restrict__ features,
    const float* __restrict__ S,
    const __hip_bfloat16* __restrict__ wt,
    const float* __restrict__ bJ, const float* __restrict__ bI,
    const float* __restrict__ ib1, const float* __restrict__ ib2,
    const float* __restrict__ gate, const float* __restrict__ bint,
    const float* __restrict__ ab1, const float* __restrict__ ab2,
    const float* __restrict__ ob1, const float* __restrict__ ob2,
    const float* __restrict__ Wout, const float* __restrict__ bout,
    float* __restrict__ out_e, float* __restrict__ out_f)
{
  __shared__ __align__(16) __hip_bfloat16 bufA[64][LDP];
  __shared__ __align__(16) __hip_bfloat16 bufB[64][LDP];
  __shared__ __align__(16) __hip_bfloat16 xfb[64][LDP];
  __shared__ float mskl[64];

  const int t     = threadIdx.x;
  const int lane  = t & 63;
  const int w     = t >> 6;
  const int wrow0 = w * 16;
  const int base  = blockIdx.x * 64;

  // stage features: raw bf16 -> xfb, softplus bf16 -> bufA
  for (int it = 0; it < 20; it++){
    int idx = it * 64 + lane;
    int row = idx / FDIM, col = idx - row * FDIM;
    float v = features[(size_t)(base + wrow0 + row) * FDIM + col];
    xfb [wrow0 + row][col] = tob(v);
    bufA[wrow0 + row][col] = tob(sp_f(v));
  }
  // zero K-pad cols [80,96) in all three tiles
  if (lane < 48){
    int arr = lane >> 4, col = FDIM + (lane & 15);
    for (int r = 0; r < 16; r++){
      if      (arr == 0) bufA[wrow0 + r][col] = tob(0.f);
      else if (arr == 1) bufB[wrow0 + r][col] = tob(0.f);
      else               xfb [wrow0 + r][col] = tob(0.f);
    }
  }
  if (t < 64) mskl[t] = (species[base + t] != -1) ? 1.f : 0.f;
  __syncthreads();

  const int j0   = lane & 15;
  const int g    = lane >> 4;
  const int kb   = g * 8;
  const int arow = wrow0 + j0;      // A-frag row for this lane
  const int r0   = wrow0 + g * 4;   // first C row for this lane

  f32x4 cur[5];

  // proto = sp(sp(f)@WJ+bJ) * S + (f@WI+bI)*mask
  {
    f32x4 accJ[5], accI[5];
    mfma_layer(accJ, bufA, arow, kb, j0, wt + (size_t)0*FDIM*WROW, bJ);
    mfma_layer(accI, xfb , arow, kb, j0, wt + (size_t)1*FDIM*WROW, bI);
    __syncthreads();   // bufA reads done before overwrite
    #pragma unroll
    for (int nt = 0; nt < 5; nt++){
      int col = 16*nt + j0;
      #pragma unroll
      for (int i = 0; i < 4; i++){
        float Sv = S[(size_t)(base + r0 + i) * FDIM + col];
        float m  = mskl[r0 + i];
        cur[nt][i] = sp_f(accJ[nt][i]) * Sv + accI[nt][i] * m;
        bufA[r0 + i][col] = tob(cur[nt][i]);
      }
    }
  }
  __syncthreads();

  // message = res_stack(proto, iW)
  #pragma unroll 1
  for (int ir = 0; ir < 3; ir++)
    res_mfma(cur, bufA, bufB, arow, kb, j0, r0,
             wt + (size_t)(3+2*ir)*FDIM*WROW, ib1 + ir*FDIM,
             wt + (size_t)(4+2*ir)*FDIM*WROW, ib2 + ir*FDIM);

  // nd = f*gate + sp(message)@Wint + bint   (no softplus on nd)
  {
    #pragma unroll
    for (int nt = 0; nt < 5; nt++){
      int col = 16*nt + j0;
      #pragma unroll
      for (int i = 0; i < 4; i++) bufB[r0 + i][col] = tob(sp_f(cur[nt][i]));
    }
    __syncthreads();
    f32x4 acc[5];
    mfma_layer(acc, bufB, arow, kb, j0, wt + (size_t)2*FDIM*WROW, bint);
    #pragma unroll
    for (int nt = 0; nt < 5; nt++){
      int col = 16*nt + j0;
      float gj = gate[col];
      #pragma unroll
      for (int i = 0; i < 4; i++){
        float xv = __bfloat162float(xfb[r0 + i][col]);
        cur[nt][i] = xv * gj + acc[nt][i];
        bufA[r0 + i][col] = tob(cur[nt][i]);
      }
    }
    __syncthreads();
  }

  // nd = res_stack(nd, aW)
  #pragma unroll 1
  for (int ir = 0; ir < 3; ir++)
    res_mfma(cur, bufA, bufB, arow, kb, j0, r0,
             wt + (size_t)(9+2*ir)*FDIM*WROW, ab1 + ir*FDIM,
             wt + (size_t)(10+2*ir)*FDIM*WROW, ab2 + ir*FDIM);

  // out_features = nd * mask
  #pragma unroll
  for (int nt = 0; nt < 5; nt++){
    int col = 16*nt + j0;
    #pragma unroll
    for (int i = 0; i < 4; i++)
      out_f[(size_t)(base + r0 + i) * FDIM + col] = cur[nt][i] * mskl[r0 + i];
  }

  // t3 = res_stack(nd, oW)
  #pragma unroll 1
  for (int ir = 0; ir < 3; ir++)
    res_mfma(cur, bufA, bufB, arow, kb, j0, r0,
             wt + (size_t)(15+2*ir)*FDIM*WROW, ob1 + ir*FDIM,
             wt + (size_t)(16+2*ir)*FDIM*WROW, ob2 + ir*FDIM);

  // energies = (sp(t3) @ Wout + bout) * mask
  {
    float ev[4] = {0.f, 0.f, 0.f, 0.f};
    #pragma unroll
    for (int nt = 0; nt < 5; nt++){
      float wv = Wout[16*nt + j0];
      #pragma unroll
      for (int i = 0; i < 4; i++) ev[i] += sp_f(cur[nt][i]) * wv;
    }
    #pragma unroll
    for (int off = 1; off < 16; off <<= 1){
      #pragma unroll
      for (int i = 0; i < 4; i++) ev[i] += __shfl_xor(ev[i], off);
    }
    if (j0 == 0){
      float b0 = bout[0];
      #pragma unroll
      for (int i = 0; i < 4; i++)
        out_e[base + r0 + i] = (ev[i] + b0) * mskl[r0 + i];
    }
  }
}

// ---------------------------------------------------------------------------
extern "C" void kernel_launch(void* const* d_in, const int* in_sizes, int n_in,
                              void* d_out, int out_size, void* d_ws, size_t ws_size,
                              hipStream_t stream) {
  const int*   species  = (const int*)  d_in[0];
  const float* features = (const float*)d_in[1];
  const float* aev      = (const float*)d_in[2];
  const int*   idx12    = (const int*)  d_in[3];
  const float* WI   = (const float*)d_in[4];  const float* bI   = (const float*)d_in[5];
  const float* Wg   = (const float*)d_in[6];  const float* bg   = (const float*)d_in[7];
  const float* WJ   = (const float*)d_in[8];  const float* bJ   = (const float*)d_in[9];
  const float* iW1  = (const float*)d_in[10]; const float* ib1  = (const float*)d_in[11];
  const float* iW2  = (const float*)d_in[12]; const float* ib2  = (const float*)d_in[13];
  const float* gate = (const float*)d_in[14];
  const float* Wint = (const float*)d_in[15]; const float* bint = (const float*)d_in[16];
  const float* aW1  = (const float*)d_in[17]; const float* ab1  = (const float*)d_in[18];
  const float* aW2  = (const float*)d_in[19]; const float* ab2  = (const float*)d_in[20];
  const float* oW1  = (const float*)d_in[21]; const float* ob1  = (const float*)d_in[22];
  const float* oW2  = (const float*)d_in[23]; const float* ob2  = (const float*)d_in[24];
  const float* Wout = (const float*)d_in[25]; const float* bout = (const float*)d_in[26];

  const int N = in_sizes[1] / FDIM;   // 16384
  const int P = in_sizes[2] / RDIM;   // 393216

  float* R   = (float*)d_ws;                           // N*20
  float* deg = R + (size_t)N * RDIM;                   // N
  float* S   = deg + N;                                // N*80
  __hip_bfloat16* wt = (__hip_bfloat16*)(S + (size_t)N * FDIM);  // 21*80*96 bf16

  float* out_e = (float*)d_out;
  float* out_f = out_e + N;

  hipMemsetAsync(R, 0, (size_t)N * (RDIM + 1) * sizeof(float), stream);

  WPtrs wp;
  wp.p[0] = WJ; wp.p[1] = WI; wp.p[2] = Wint;
  for (int ir = 0; ir < 3; ir++){
    wp.p[3  + 2*ir] = iW1 + ir*FDIM*FDIM; wp.p[4  + 2*ir] = iW2 + ir*FDIM*FDIM;
    wp.p[9  + 2*ir] = aW1 + ir*FDIM*FDIM; wp.p[10 + 2*ir] = aW2 + ir*FDIM*FDIM;
    wp.p[15 + 2*ir] = oW1 + ir*FDIM*FDIM; wp.p[16 + 2*ir] = oW2 + ir*FDIM*FDIM;
  }
  prep_weights<<<21, 256, 0, stream>>>(wp, wt);

  scatter_R<<<(P * RDIM + 255) / 256, 256, 0, stream>>>(aev, idx12, R, P);
  deg_kernel<<<(P + 255) / 256, 256, 0, stream>>>(idx12, deg, P);
  aevt_kernel<<<(N + 63) / 64, TPB2, 0, stream>>>(R, deg, Wg, bg, S, N);

  atom_mfma<<<(N + 63) / 64, 256, 0, stream>>>(species, features, S, wt,
      bJ, bI, ib1, ib2, gate, bint, ab1, ab2, ob1, ob2, Wout, bout, out_e, out_f);
}

// Round 4
// 170.072 us; speedup vs baseline: 4.1950x; 1.3615x over previous
//
#include <hip/hip_runtime.h>
#include <hip/hip_bf16.h>

#define FDIM 80
#define RDIM 20
#define RD1  21      // RDIM + 1 (deg folded in)
#define LDP  104     // LDS row stride (bf16)
#define WROW 96      // Wt row stride (bf16), K padded to 96

typedef float  f32x4  __attribute__((ext_vector_type(4)));
typedef short  bf16x8 __attribute__((ext_vector_type(8)));

__device__ __forceinline__ float sp_f(float x){
  float e = __expf(-fabsf(x));
  return fmaxf(x, 0.f) + __logf(1.f + e);
}
__device__ __forceinline__ __hip_bfloat16 tob(float x){ return __float2bfloat16(x); }

// ---------------------------------------------------------------------------
// Weight prep: Wt[slot][j][k] = bf16(W[k][j]), zero-padded k in [80,96)
// ---------------------------------------------------------------------------
struct WPtrs { const float* p[21]; };

__global__ __launch_bounds__(256) void prep_weights(WPtrs wp, __hip_bfloat16* __restrict__ wt){
  const float* W = wp.p[blockIdx.x];
  __hip_bfloat16* dst = wt + (size_t)blockIdx.x * FDIM * WROW;
  for (int i = threadIdx.x; i < FDIM * WROW; i += 256){
    int j = i / WROW, k = i - j * WROW;
    dst[i] = __float2bfloat16(k < FDIM ? W[k * FDIM + j] : 0.f);
  }
}

// ---------------------------------------------------------------------------
// Scatter: for each (pair,side): R2[n][0..19] += aev[p][..], R2[n][20] += 1
// ---------------------------------------------------------------------------
__global__ __launch_bounds__(256) void scatter_R2(const float* __restrict__ aev,
    const int* __restrict__ idx12, float* __restrict__ R2, int P){
  int g = blockIdx.x * 256 + threadIdx.x;
  if (g >= P * RD1) return;
  int p = g / RD1, r = g - p * RD1;
  float v = (r < RDIM) ? aev[(size_t)p * RDIM + r] : 1.f;
  int i1 = idx12[p], i2 = idx12[P + p];
  atomicAdd(&R2[(size_t)i1 * RD1 + r], v);
  atomicAdd(&R2[(size_t)i2 * RD1 + r], v);
}

// ---------------------------------------------------------------------------
// S[n] = R2[n][0:20] @ Wg + R2[n][20]*bg
// ---------------------------------------------------------------------------
#define TPB2 320
__global__ __launch_bounds__(TPB2) void aevt_kernel(const float* __restrict__ R2,
    const float* __restrict__ Wg, const float* __restrict__ bg,
    float* __restrict__ S, int N)
{
  __shared__ float Rl[64][RD1];
  const int t = threadIdx.x;
  const int base = blockIdx.x * 64;
  for (int i = t; i < 64 * RD1; i += TPB2){
    int u = i / RD1, r = i - u * RD1;
    Rl[u][r] = R2[(size_t)(base + u) * RD1 + r];
  }
  const int j = t % FDIM, rg = t / FDIM;
  float wc[RDIM];
  #pragma unroll
  for (int r = 0; r < RDIM; r++) wc[r] = Wg[r * FDIM + j];
  float bgj = bg[j];
  __syncthreads();
  #pragma unroll 1
  for (int ui = 0; ui < 16; ui++){
    int u = rg + 4 * ui;
    float acc = Rl[u][RDIM] * bgj;
    #pragma unroll
    for (int r = 0; r < RDIM; r++) acc += Rl[u][r] * wc[r];
    S[(size_t)(base + u) * FDIM + j] = acc;
  }
}

// ---------------------------------------------------------------------------
// MFMA layer: batch-load B-frags to regs, then MFMA chain.
// A-frag: m=lane&15, k=(lane>>4)*8+e (+32ks). C/D: col=lane&15+16nt,
// row=(lane>>4)*4+i.  nt range [ntbase, ntbase+nnt), nnt in {2,3}.
// ---------------------------------------------------------------------------
__device__ __forceinline__ void mfma_layer(f32x4 acc[3],
    const __hip_bfloat16 (*in)[LDP], int arow, int kb, int j0,
    int ntbase, int nnt,
    const __hip_bfloat16* __restrict__ wtm, const float* __restrict__ bias)
{
  bf16x8 bfr[3][3];
  #pragma unroll
  for (int q = 0; q < 3; q++) if (q < nnt){
    #pragma unroll
    for (int ks = 0; ks < 3; ks++)
      bfr[q][ks] = *(const bf16x8*)(const void*)
          &wtm[(size_t)(16*(ntbase+q) + j0) * WROW + kb + ks*32];
  }
  bf16x8 a[3];
  #pragma unroll
  for (int ks = 0; ks < 3; ks++)
    a[ks] = *(const bf16x8*)(const void*)&in[arow][kb + ks*32];
  #pragma unroll
  for (int q = 0; q < 3; q++) if (q < nnt){
    float b = bias[16*(ntbase+q) + j0];
    acc[q] = (f32x4){b, b, b, b};
  }
  #pragma unroll
  for (int ks = 0; ks < 3; ks++){
    #pragma unroll
    for (int q = 0; q < 3; q++) if (q < nnt)
      acc[q] = __builtin_amdgcn_mfma_f32_16x16x32_bf16(a[ks], bfr[q][ks], acc[q], 0, 0, 0);
  }
}

__device__ __forceinline__ void res_mfma(f32x4 cur[3],
    __hip_bfloat16 (*bA)[LDP], __hip_bfloat16 (*bB)[LDP],
    int arow, int kb, int j0, int r0, int ntbase, int nnt,
    const __hip_bfloat16* __restrict__ w1, const float* __restrict__ b1,
    const __hip_bfloat16* __restrict__ w2, const float* __restrict__ b2)
{
  f32x4 acc[3];
  mfma_layer(acc, bA, arow, kb, j0, ntbase, nnt, w1, b1);
  #pragma unroll
  for (int q = 0; q < 3; q++) if (q < nnt){
    int col = 16*(ntbase+q) + j0;
    #pragma unroll
    for (int i = 0; i < 4; i++) bB[r0 + i][col] = tob(sp_f(acc[q][i]));
  }
  __syncthreads();
  mfma_layer(acc, bB, arow, kb, j0, ntbase, nnt, w2, b2);
  #pragma unroll
  for (int q = 0; q < 3; q++) if (q < nnt){
    int col = 16*(ntbase+q) + j0;
    #pragma unroll
    for (int i = 0; i < 4; i++){
      cur[q][i] = sp_f(acc[q][i] + cur[q][i]);
      bA[r0 + i][col] = tob(cur[q][i]);
    }
  }
  __syncthreads();
}

// ---------------------------------------------------------------------------
// Atom kernel: 64 atoms/block, 8 waves = 4 row-strips x 2 col-groups
// ---------------------------------------------------------------------------
__global__ __launch_bounds__(512) void atom_mfma(
    const int*   __restrict__ species,
    const float* __restrict__ features,
    const float* __restrict__ S,
    const __hip_bfloat16* __restrict__ wt,
    const float* __restrict__ bJ, const float* __restrict__ bI,
    const float* __restrict__ ib1, const float* __restrict__ ib2,
    const float* __restrict__ gate, const float* __restrict__ bint,
    const float* __restrict__ ab1, const float* __restrict__ ab2,
    const float* __restrict__ ob1, const float* __restrict__ ob2,
    const float* __restrict__ Wout, const float* __restrict__ bout,
    float* __restrict__ out_e, float* __restrict__ out_f)
{
  __shared__ __align__(16) __hip_bfloat16 bufA[64][LDP];
  __shared__ __align__(16) __hip_bfloat16 bufB[64][LDP];
  __shared__ __align__(16) __hip_bfloat16 xfb[64][LDP];
  __shared__ float mskl[64];
  __shared__ float evp[2][64];

  const int t     = threadIdx.x;
  const int lane  = t & 63;
  const int w     = t >> 6;        // 0..7
  const int strip = w & 3;         // row strip
  const int cg    = w >> 2;        // column group
  const int wrow0 = strip * 16;
  const int base  = blockIdx.x * 64;

  const int ntbase = cg ? 3 : 0;
  const int nnt    = cg ? 2 : 3;

  // stage features: raw bf16 -> xfb, softplus bf16 -> bufA  (coalesced)
  for (int i = t; i < 64 * FDIM; i += 512){
    int row = i / FDIM, col = i - row * FDIM;
    float v = features[(size_t)(base + row) * FDIM + col];
    xfb [row][col] = tob(v);
    bufA[row][col] = tob(sp_f(v));
  }
  // zero K-pad cols [80,96) in all three tiles
  for (int i = t; i < 3 * 64 * 16; i += 512){
    int b = i >> 10, rem = i & 1023;
    int row = rem >> 4, col = FDIM + (rem & 15);
    if      (b == 0) bufA[row][col] = tob(0.f);
    else if (b == 1) bufB[row][col] = tob(0.f);
    else             xfb [row][col] = tob(0.f);
  }
  if (t < 64) mskl[t] = (species[base + t] != -1) ? 1.f : 0.f;
  __syncthreads();

  const int j0   = lane & 15;
  const int g    = lane >> 4;
  const int kb   = g * 8;
  const int arow = wrow0 + j0;
  const int r0   = wrow0 + g * 4;

  f32x4 cur[3];

  // proto = sp(sp(f)@WJ+bJ) * S + (f@WI+bI)*mask
  {
    f32x4 accJ[3], accI[3];
    mfma_layer(accJ, bufA, arow, kb, j0, ntbase, nnt, wt + (size_t)0*FDIM*WROW, bJ);
    mfma_layer(accI, xfb , arow, kb, j0, ntbase, nnt, wt + (size_t)1*FDIM*WROW, bI);
    __syncthreads();   // bufA reads done before overwrite
    #pragma unroll
    for (int q = 0; q < 3; q++) if (q < nnt){
      int col = 16*(ntbase+q) + j0;
      #pragma unroll
      for (int i = 0; i < 4; i++){
        float Sv = S[(size_t)(base + r0 + i) * FDIM + col];
        float m  = mskl[r0 + i];
        cur[q][i] = sp_f(accJ[q][i]) * Sv + accI[q][i] * m;
        bufA[r0 + i][col] = tob(cur[q][i]);
      }
    }
  }
  __syncthreads();

  // message = res_stack(proto, iW)
  #pragma unroll 1
  for (int ir = 0; ir < 3; ir++)
    res_mfma(cur, bufA, bufB, arow, kb, j0, r0, ntbase, nnt,
             wt + (size_t)(3+2*ir)*FDIM*WROW, ib1 + ir*FDIM,
             wt + (size_t)(4+2*ir)*FDIM*WROW, ib2 + ir*FDIM);

  // nd = f*gate + sp(message)@Wint + bint
  {
    #pragma unroll
    for (int q = 0; q < 3; q++) if (q < nnt){
      int col = 16*(ntbase+q) + j0;
      #pragma unroll
      for (int i = 0; i < 4; i++) bufB[r0 + i][col] = tob(sp_f(cur[q][i]));
    }
    __syncthreads();
    f32x4 acc[3];
    mfma_layer(acc, bufB, arow, kb, j0, ntbase, nnt, wt + (size_t)2*FDIM*WROW, bint);
    #pragma unroll
    for (int q = 0; q < 3; q++) if (q < nnt){
      int col = 16*(ntbase+q) + j0;
      float gj = gate[col];
      #pragma unroll
      for (int i = 0; i < 4; i++){
        float xv = __bfloat162float(xfb[r0 + i][col]);
        cur[q][i] = xv * gj + acc[q][i];
        bufA[r0 + i][col] = tob(cur[q][i]);
      }
    }
    __syncthreads();
  }

  // nd = res_stack(nd, aW)
  #pragma unroll 1
  for (int ir = 0; ir < 3; ir++)
    res_mfma(cur, bufA, bufB, arow, kb, j0, r0, ntbase, nnt,
             wt + (size_t)(9+2*ir)*FDIM*WROW, ab1 + ir*FDIM,
             wt + (size_t)(10+2*ir)*FDIM*WROW, ab2 + ir*FDIM);

  // out_features = nd * mask
  #pragma unroll
  for (int q = 0; q < 3; q++) if (q < nnt){
    int col = 16*(ntbase+q) + j0;
    #pragma unroll
    for (int i = 0; i < 4; i++)
      out_f[(size_t)(base + r0 + i) * FDIM + col] = cur[q][i] * mskl[r0 + i];
  }

  // t3 = res_stack(nd, oW)
  #pragma unroll 1
  for (int ir = 0; ir < 3; ir++)
    res_mfma(cur, bufA, bufB, arow, kb, j0, r0, ntbase, nnt,
             wt + (size_t)(15+2*ir)*FDIM*WROW, ob1 + ir*FDIM,
             wt + (size_t)(16+2*ir)*FDIM*WROW, ob2 + ir*FDIM);

  // energies = (sp(t3) @ Wout + bout) * mask   (reduce over j0, then cg)
  {
    float ev[4] = {0.f, 0.f, 0.f, 0.f};
    #pragma unroll
    for (int q = 0; q < 3; q++) if (q < nnt){
      float wv = Wout[16*(ntbase+q) + j0];
      #pragma unroll
      for (int i = 0; i < 4; i++) ev[i] += sp_f(cur[q][i]) * wv;
    }
    #pragma unroll
    for (int off = 1; off < 16; off <<= 1){
      #pragma unroll
      for (int i = 0; i < 4; i++) ev[i] += __shfl_xor(ev[i], off);
    }
    if (j0 == 0){
      #pragma unroll
      for (int i = 0; i < 4; i++) evp[cg][r0 + i] = ev[i];
    }
  }
  __syncthreads();
  if (t < 64)
    out_e[base + t] = (evp[0][t] + evp[1][t] + bout[0]) * mskl[t];
}

// ---------------------------------------------------------------------------
extern "C" void kernel_launch(void* const* d_in, const int* in_sizes, int n_in,
                              void* d_out, int out_size, void* d_ws, size_t ws_size,
                              hipStream_t stream) {
  const int*   species  = (const int*)  d_in[0];
  const float* features = (const float*)d_in[1];
  const float* aev      = (const float*)d_in[2];
  const int*   idx12    = (const int*)  d_in[3];
  const float* WI   = (const float*)d_in[4];  const float* bI   = (const float*)d_in[5];
  const float* Wg   = (const float*)d_in[6];  const float* bg   = (const float*)d_in[7];
  const float* WJ   = (const float*)d_in[8];  const float* bJ   = (const float*)d_in[9];
  const float* iW1  = (const float*)d_in[10]; const float* ib1  = (const float*)d_in[11];
  const float* iW2  = (const float*)d_in[12]; const float* ib2  = (const float*)d_in[13];
  const float* gate = (const float*)d_in[14];
  const float* Wint = (const float*)d_in[15]; const float* bint = (const float*)d_in[16];
  const float* aW1  = (const float*)d_in[17]; const float* ab1  = (const float*)d_in[18];
  const float* aW2  = (const float*)d_in[19]; const float* ab2  = (const float*)d_in[20];
  const float* oW1  = (const float*)d_in[21]; const float* ob1  = (const float*)d_in[22];
  const float* oW2  = (const float*)d_in[23]; const float* ob2  = (const float*)d_in[24];
  const float* Wout = (const float*)d_in[25]; const float* bout = (const float*)d_in[26];

  const int N = in_sizes[1] / FDIM;   // 16384
  const int P = in_sizes[2] / RDIM;   // 393216

  float* R2 = (float*)d_ws;                            // N*21
  float* S  = R2 + (size_t)N * RD1;                    // N*80
  __hip_bfloat16* wt = (__hip_bfloat16*)(S + (size_t)N * FDIM);  // 21*80*96 bf16

  float* out_e = (float*)d_out;
  float* out_f = out_e + N;

  hipMemsetAsync(R2, 0, (size_t)N * RD1 * sizeof(float), stream);

  WPtrs wp;
  wp.p[0] = WJ; wp.p[1] = WI; wp.p[2] = Wint;
  for (int ir = 0; ir < 3; ir++){
    wp.p[3  + 2*ir] = iW1 + ir*FDIM*FDIM; wp.p[4  + 2*ir] = iW2 + ir*FDIM*FDIM;
    wp.p[9  + 2*ir] = aW1 + ir*FDIM*FDIM; wp.p[10 + 2*ir] = aW2 + ir*FDIM*FDIM;
    wp.p[15 + 2*ir] = oW1 + ir*FDIM*FDIM; wp.p[16 + 2*ir] = oW2 + ir*FDIM*FDIM;
  }
  prep_weights<<<21, 256, 0, stream>>>(wp, wt);

  scatter_R2<<<((size_t)P * RD1 + 255) / 256, 256, 0, stream>>>(aev, idx12, R2, P);
  aevt_kernel<<<(N + 63) / 64, TPB2, 0, stream>>>(R2, Wg, bg, S, N);

  atom_mfma<<<(N + 63) / 64, 512, 0, stream>>>(species, features, S, wt,
      bJ, bI, ib1, ib2, gate, bint, ab1, ab2, ob1, ob2, Wout, bout, out_e, out_f);
}